// Round 9
// baseline (258.646 us; speedup 1.0000x reference)
//
#include <hip/hip_runtime.h>
#include <hip/hip_bf16.h>
#include <stdint.h>
#include <stddef.h>

// Problem constants (B=2, L=2048, D=32, H=8)
#define LL 2048

typedef __attribute__((ext_vector_type(8))) short short8;
typedef __attribute__((ext_vector_type(4))) float f32x4;
typedef unsigned short ushort_t;
typedef unsigned int uint_t;

// ws layout (float elements). Total ~17.9 MB.
#define VAOFF   1048576u   // V_agg f32 [bh][l][d]
#define QS16OFF 2097152u   // Q*scale*log2e bf16 [bh][l][d]
#define KS16OFF 2621440u   // K*grade_signs bf16 [bh][l][d]
#define KG16OFF 3145728u   // K raw bf16 [bh][l][d]
#define VT16OFF 3670016u   // V^T bf16 [bh*32+d][l] (key-permuted)
#define RVOFF   4194304u   // row_valid f32, B*L
#define MBOFF   4198400u   // packed mask bits [row][ks][kt], 262144 uint32
#define C2TOFF  4460544u   // cayley^T bf16 [k][ij], 32768 elems

__device__ __forceinline__ ushort_t f2bf(float f) {
    unsigned int u = __float_as_uint(f);
    u += 0x7FFFu + ((u >> 16) & 1u);   // RNE
    return (ushort_t)(u >> 16);
}
__device__ __forceinline__ float bf2f(ushort_t s) {
    return __uint_as_float(((unsigned int)s) << 16);
}
__device__ __forceinline__ uint_t pkbf(float a, float b) {   // RNE pack (one-time)
    __hip_bfloat162 h = __float22bfloat162_rn(float2{a, b});
    return *(uint_t*)&h;
}
// cheap add-half-rounded bf16 pair pack (hot loops)
__device__ __forceinline__ uint_t pk2(float a, float b) {
    const uint_t ua = (__float_as_uint(a) + 0x8000u) >> 16;
    const uint_t ub = (__float_as_uint(b) + 0x8000u) & 0xFFFF0000u;
    return ua | ub;
}

// ---------------------------------------------------------------------------
// Fused prep: blocks [0,1024) mask detect+bit-pack (NEW word order within a
// row: index = ks*16 + kt so each attn wave's 16 words are contiguous);
// [1024,1536) QKV projection, 8 positions/block (W re-reads halved) with
// direct permuted-V^T emission; [1536,1540) cayley^T bf16.
// All three branches write disjoint ws regions and read only inputs.
// ---------------------------------------------------------------------------
__global__ __launch_bounds__(256) void prep_kernel(
        const uint_t* __restrict__ mraw, uint_t* __restrict__ mb,
        const float* __restrict__ x,
        const float* __restrict__ Wq, const float* __restrict__ Wk,
        const float* __restrict__ Wv, const float* __restrict__ gs,
        const float* __restrict__ cayley, float* __restrict__ ws) {
    __shared__ float smem[8192];
    const int t = threadIdx.x;

    if (blockIdx.x < 1024) {
        // ---------------- mask detect + bit-pack ----------------
        int* sI = (int*)smem;
        int* sF = ((int*)smem) + 1;
        if (t == 0) { *sI = 1; *sF = 1; }
        __syncthreads();
        const size_t blk = blockIdx.x;
        const uint4* p8 = (const uint4*)(mraw + blk * 2048 + t * 8);
        const uint4 a = p8[0], c = p8[1];
        const uint_t d8[8] = {a.x, a.y, a.z, a.w, c.x, c.y, c.z, c.w};
        int oi = 1, of = 1;
#pragma unroll
        for (int i = 0; i < 8; ++i) {
            if (d8[i] > 1u) oi = 0;
            if (d8[i] != 0u && d8[i] != 0x3F800000u) of = 0;
        }
        if (!oi) atomicAnd(sI, 0);
        if (!of) atomicAnd(sF, 0);
        __syncthreads();
        const int mtype = *sI ? 1 : (*sF ? 2 : 0);
        uint_t w = 0;
        if (mtype == 0) {
#pragma unroll
            for (int i = 0; i < 8; ++i) {
#pragma unroll
                for (int by = 0; by < 4; ++by)
                    w |= (((d8[i] >> (8 * by)) & 0xFFu) ? 1u : 0u) << (i * 4 + by);
            }
        } else {
            const uint4* pi = (const uint4*)(mraw + blk * 8192 + (size_t)t * 32);
#pragma unroll
            for (int i = 0; i < 8; ++i) {
                const uint4 d = pi[i];
                if (mtype == 1) {
                    w |= (d.x << (i * 4)) | (d.y << (i * 4 + 1)) |
                         (d.z << (i * 4 + 2)) | (d.w << (i * 4 + 3));
                } else {
                    w |= ((d.x ? 1u : 0u) << (i * 4)) | ((d.y ? 1u : 0u) << (i * 4 + 1)) |
                         ((d.z ? 1u : 0u) << (i * 4 + 2)) | ((d.w ? 1u : 0u) << (i * 4 + 3));
                }
            }
        }
        // reorder within row: old word w0 = W&63 (key/32), new = (w0&3)*16 + (w0>>2)
        const uint_t W = (uint_t)(blk * 256 + t);
        const uint_t w0 = W & 63u;
        mb[(W & ~63u) | (((w0 & 3u) << 4) | (w0 >> 2))] = w;
    } else if (blockIdx.x < 1536) {
        // ---------------- QKV projection, 8 positions/block ----------------
        ushort_t* Qs16 = (ushort_t*)(ws + QS16OFF);
        ushort_t* Ks16 = (ushort_t*)(ws + KS16OFF);
        ushort_t* Kg16 = (ushort_t*)(ws + KG16OFF);
        ushort_t* Vt   = (ushort_t*)(ws + VT16OFF);
        float* sX = smem;
        const int pid0 = (blockIdx.x - 1024) * 8;
        if (t < 64) ((float4*)sX)[t] = ((const float4*)(x + (size_t)pid0 * 32))[t];
        float wq[32], wk[32], wv[32];
        const float4* wqp = (const float4*)(Wq + t * 32);
        const float4* wkp = (const float4*)(Wk + t * 32);
        const float4* wvp = (const float4*)(Wv + t * 32);
#pragma unroll
        for (int d4 = 0; d4 < 8; ++d4) {
            float4 a = wqp[d4]; wq[4*d4]=a.x; wq[4*d4+1]=a.y; wq[4*d4+2]=a.z; wq[4*d4+3]=a.w;
            float4 b = wkp[d4]; wk[4*d4]=b.x; wk[4*d4+1]=b.y; wk[4*d4+2]=b.z; wk[4*d4+3]=b.w;
            float4 c = wvp[d4]; wv[4*d4]=c.x; wv[4*d4+1]=c.y; wv[4*d4+2]=c.z; wv[4*d4+3]=c.w;
        }
        const float sgn = gs[t & 31];
        // q scale folded with log2(e): exp2 in attn computes e^s
        const float qscale = 0.17677669529663687f * 1.4426950408889634f;
        const int h = t >> 5, dd = t & 31;
        const int b0 = pid0 >> 11, l0 = pid0 & 2047;
        __syncthreads();
        ushort4 vt4[2];
        for (int r = 0; r < 8; ++r) {
            const int pid = pid0 + r;
            const int b = pid >> 11, l = pid & 2047;
            float q = 0.f, k = 0.f, v = 0.f;
#pragma unroll
            for (int d = 0; d < 32; ++d) {
                const float xv = sX[r * 32 + d];
                q += xv * wq[d]; k += xv * wk[d]; v += xv * wv[d];
            }
            const size_t o = ((size_t)((b * 8 + h) * 2048 + l)) * 32 + dd;
            Qs16[o] = f2bf(q * qscale);
            Ks16[o] = f2bf(k * sgn);
            Kg16[o] = f2bf(k);
            ((ushort_t*)&vt4[r >> 2])[r & 3] = f2bf(v);
        }
        // permuted Vt columns: per 4-group base (l0+g4*4 is 4-aligned)
        ushort_t* vtrow = Vt + ((size_t)((b0 * 8 + h) * 32 + dd)) * 2048;
#pragma unroll
        for (int g4 = 0; g4 < 2; ++g4) {
            const int lg = l0 + g4 * 4;
            const int lloc = lg & 63;
            const int g = lloc >> 5, tt = (lloc >> 4) & 1, q4 = (lloc >> 2) & 3;
            const int pc = (lg & ~63) + g * 32 + q4 * 8 + tt * 4;
            *(ushort4*)(vtrow + pc) = vt4[g4];
        }
    } else {
        // ---------------- cayley^T bf16 ----------------
        float* sC = smem;
        ushort_t* C2t = (ushort_t*)(ws + C2TOFF);
        const int ij0 = (blockIdx.x - 1536) * 256;   // ij in [0,1024)
#pragma unroll
        for (int i = 0; i < 8; ++i)
            ((float4*)sC)[t + i * 256] = ((const float4*)(cayley + (size_t)ij0 * 32))[t + i * 256];
        __syncthreads();
        const int k = t & 31, jc = t >> 5;
        uint_t pk[16];
#pragma unroll
        for (int j2 = 0; j2 < 16; ++j2) {
            pk[j2] = pkbf(sC[(jc * 32 + 2 * j2) * 32 + k], sC[(jc * 32 + 2 * j2 + 1) * 32 + k]);
        }
        uint_t* dst = (uint_t*)(C2t + (size_t)k * 1024 + ij0 + jc * 32);
#pragma unroll
        for (int j2 = 0; j2 < 16; ++j2) dst[j2] = pk[j2];
    }
}

// ---------------------------------------------------------------------------
// Barrier-free MFMA attention, round 9: r8 structure (8 waves, 4-way key
// split, 32 waves/CU) plus:
//  * all 16 mask words hoisted to registers pre-loop (4x dwordx4, contiguous
//    in the new mb layout); kt loop fully unrolled so they const-fold.
//  * exp2f instead of __expf (log2e folded into Qs by prep).
// ---------------------------------------------------------------------------
__global__ __launch_bounds__(512, 8) void attn_kernel(
        const uint_t* __restrict__ mb, float* __restrict__ ws) {
    const ushort_t* Qs = (const ushort_t*)(ws + QS16OFF);
    const ushort_t* Ks = (const ushort_t*)(ws + KS16OFF);
    const ushort_t* Vt = (const ushort_t*)(ws + VT16OFF);
    float* Va = ws + VAOFF;
    float* Rv = ws + RVOFF;

    // swizzle: bh = ((bid&7)<<1)|bit9, q0 = ((bid>>3)&63)*32  (bijective)
    const int bid = blockIdx.x;
    const int bh = ((bid & 7) << 1) | ((bid >> 9) & 1);
    const int q0 = ((bid >> 3) & 63) * 32;
    const int b = bh >> 3;
    const int t = threadIdx.x;
    const int w = t >> 6, lane = t & 63;
    const int quad = lane >> 4, l15 = lane & 15;
    const int rh = w & 1, ks = w >> 1;         // ks in 0..3

    __shared__ float accb[3][2][64][8];
    __shared__ float psL[4][32];

    const short8 qf = *(const short8*)(Qs +
        ((size_t)(bh * 2048 + q0 + rh * 16 + l15)) * 32 + quad * 8);

    const ushort_t* ka_p = Ks + (size_t)bh * 65536 + (ks * 32 + l15) * 32 + quad * 8;
    const ushort_t* v0_p = Vt + (size_t)bh * 65536 + (size_t)l15 * 2048 + ks * 32 + quad * 8;

    // mask words for this wave's (row, ks): contiguous 16 dwords
    const uint4* mp4 = (const uint4*)(mb +
        ((size_t)b * 2048 + q0 + rh * 16 + l15) * 64 + ks * 16);
    const uint4 mA = mp4[0], mB = mp4[1], mC = mp4[2], mD = mp4[3];
    const uint_t mwArr[16] = {mA.x, mA.y, mA.z, mA.w, mB.x, mB.y, mB.z, mB.w,
                              mC.x, mC.y, mC.z, mC.w, mD.x, mD.y, mD.z, mD.w};

    f32x4 acc0 = {0.f, 0.f, 0.f, 0.f};
    f32x4 acc1 = {0.f, 0.f, 0.f, 0.f};
    f32x4 acc2 = {0.f, 0.f, 0.f, 0.f};   // rowsums (col-0 lanes)
    const int bp0 = quad * 4, bp1 = 16 + quad * 4;

    union { uint_t u[4]; short8 s; } ONES;
    {
        const uint_t ov = (l15 == 0) ? 0x3F803F80u : 0u;   // bf16 1.0 pair
        ONES.u[0] = ov; ONES.u[1] = ov; ONES.u[2] = ov; ONES.u[3] = ov;
    }

#pragma unroll
    for (int kt = 0; kt < 16; ++kt) {
        const short8 ka = *(const short8*)(ka_p + kt * 4096);
        const short8 kb = *(const short8*)(ka_p + kt * 4096 + 512);
        const short8 v0 = *(const short8*)(v0_p + kt * 128);
        const short8 v1 = *(const short8*)(v0_p + 16 * 2048 + kt * 128);
        const uint_t mw = mwArr[kt];

        const f32x4 z = {0.f, 0.f, 0.f, 0.f};
        f32x4 s0 = __builtin_amdgcn_mfma_f32_16x16x32_bf16(ka, qf, z, 0, 0, 0);
        f32x4 s1 = __builtin_amdgcn_mfma_f32_16x16x32_bf16(kb, qf, z, 0, 0, 0);

        float p0[4], p1[4];
#pragma unroll
        for (int r = 0; r < 4; ++r) {
            p0[r] = ((mw >> (bp0 + r)) & 1u) ? exp2f(s0[r]) : 0.f;
            p1[r] = ((mw >> (bp1 + r)) & 1u) ? exp2f(s1[r]) : 0.f;
        }
        union { uint_t u[4]; short8 s; } P;
        P.u[0] = pk2(p0[0], p0[1]); P.u[1] = pk2(p0[2], p0[3]);
        P.u[2] = pk2(p1[0], p1[1]); P.u[3] = pk2(p1[2], p1[3]);

        acc0 = __builtin_amdgcn_mfma_f32_16x16x32_bf16(P.s, v0, acc0, 0, 0, 0);
        acc1 = __builtin_amdgcn_mfma_f32_16x16x32_bf16(P.s, v1, acc1, 0, 0, 0);
        acc2 = __builtin_amdgcn_mfma_f32_16x16x32_bf16(P.s, ONES.s, acc2, 0, 0, 0);
    }

    // acc2[r] (lanes l15==0) = partial rowsum of q-row quad*4+r
    if (l15 == 0) {
#pragma unroll
        for (int r = 0; r < 4; ++r) psL[ks][rh * 16 + quad * 4 + r] = acc2[r];
    }
    if (ks != 0) {
#pragma unroll
        for (int i = 0; i < 4; ++i) {
            accb[ks - 1][rh][lane][i] = acc0[i];
            accb[ks - 1][rh][lane][4 + i] = acc1[i];
        }
    }
    __syncthreads();
    if (ks == 0) {
#pragma unroll
        for (int p = 0; p < 3; ++p) {
#pragma unroll
            for (int i = 0; i < 4; ++i) {
                acc0[i] += accb[p][rh][lane][i];
                acc1[i] += accb[p][rh][lane][4 + i];
            }
        }
#pragma unroll
        for (int r = 0; r < 4; ++r) {
            const int row = rh * 16 + quad * 4 + r;
            const float tot = psL[0][row] + psL[1][row] + psL[2][row] + psL[3][row];
            const float inv = (tot > 0.f) ? 1.0f / tot : 0.f;
            const size_t o = ((size_t)(bh * 2048 + q0 + row)) * 32;
            Va[o + l15] = acc0[r] * inv;
            Va[o + 16 + l15] = acc1[r] * inv;
            if ((bh & 7) == 0 && l15 == 0)
                Rv[(size_t)b * 2048 + q0 + row] = (tot > 0.f) ? 1.0f : 0.f;
        }
    }
}

// ---------------------------------------------------------------------------
// MFMA geometric product + epilogue + Wo. sC row stride 1040 ushorts
// (bank stride 8 mod 32 -> 4-way conflicts, was 8-way at 1032).
// SQ32 scaled by ln2 to undo the log2e folded into Qs.
// ---------------------------------------------------------------------------
__global__ __launch_bounds__(256) void gp_kernel(
        const float* __restrict__ ws, const float* __restrict__ Wo,
        float* __restrict__ out) {
    const float* Va = ws + VAOFF;
    const ushort_t* Qs = (const ushort_t*)(ws + QS16OFF);
    const ushort_t* Kg = (const ushort_t*)(ws + KG16OFF);
    const ushort_t* C2t = (const ushort_t*)(ws + C2TOFF);
    const float* Rv = ws + RVOFF;
    __shared__ ushort_t sC[32 * 1040];
    __shared__ float sH[64 * 32];

    const int t = threadIdx.x;
    const int w = t >> 6, lane = t & 63;
    const int quad = lane >> 4, l15 = lane & 15;

#pragma unroll
    for (int j = 0; j < 16; ++j) {
        const int c = j * 256 + t;
        const int row = c >> 7, col = (c & 127) * 8;
        *(short8*)(&sC[row * 1040 + col]) = *(const short8*)(C2t + row * 1024 + col);
    }

    const int grow0 = blockIdx.x * 64 + w * 16 + l15;
    const int pos = grow0 >> 3, h = grow0 & 7;
    const int b = pos >> 11, l = pos & 2047;
    const size_t gb = ((size_t)((b * 8 + h) * 2048 + l)) * 32;

    float q[32];
#pragma unroll
    for (int j8 = 0; j8 < 4; ++j8) {
        const short8 qv = *(const short8*)(Qs + gb + j8 * 8);
#pragma unroll
        for (int i = 0; i < 8; ++i) q[j8 * 8 + i] = bf2f((ushort_t)qv[i]);
    }
    float u[8];
    {
        const short8 kv = *(const short8*)(Kg + gb + quad * 8);
        const float4 va0 = *(const float4*)(Va + gb + quad * 8);
        const float4 va1 = *(const float4*)(Va + gb + quad * 8 + 4);
        u[0] = va0.x + 0.25f * bf2f((ushort_t)kv[0]);
        u[1] = va0.y + 0.25f * bf2f((ushort_t)kv[1]);
        u[2] = va0.z + 0.25f * bf2f((ushort_t)kv[2]);
        u[3] = va0.w + 0.25f * bf2f((ushort_t)kv[3]);
        u[4] = va1.x + 0.25f * bf2f((ushort_t)kv[4]);
        u[5] = va1.y + 0.25f * bf2f((ushort_t)kv[5]);
        u[6] = va1.z + 0.25f * bf2f((ushort_t)kv[6]);
        u[7] = va1.w + 0.25f * bf2f((ushort_t)kv[7]);
    }
    __syncthreads();

    f32x4 a0 = {0.f, 0.f, 0.f, 0.f};
    f32x4 a1 = {0.f, 0.f, 0.f, 0.f};
    const ushort_t* b0p = sC + (size_t)l15 * 1040 + quad * 8;
    const ushort_t* b1p = sC + (size_t)(16 + l15) * 1040 + quad * 8;

#pragma unroll
    for (int kc = 0; kc < 32; ++kc) {
        const float qk = q[kc];
        union { uint_t u4[4]; short8 s; } F;
        F.u4[0] = pk2(qk * u[0], qk * u[1]);
        F.u4[1] = pk2(qk * u[2], qk * u[3]);
        F.u4[2] = pk2(qk * u[4], qk * u[5]);
        F.u4[3] = pk2(qk * u[6], qk * u[7]);
        const short8 bb0 = *(const short8*)(b0p + kc * 32);
        const short8 bb1 = *(const short8*)(b1p + kc * 32);
        a0 = __builtin_amdgcn_mfma_f32_16x16x32_bf16(F.s, bb0, a0, 0, 0, 0);
        a1 = __builtin_amdgcn_mfma_f32_16x16x32_bf16(F.s, bb1, a1, 0, 0, 0);
    }

    // undo q scale (sqrt(32)) and the folded log2e (x ln2)
    const float SQ32 = 5.656854249492381f * 0.69314718055994531f;
#pragma unroll
    for (int r = 0; r < 4; ++r) {
        const int grow = blockIdx.x * 64 + w * 16 + quad * 4 + r;
        const int pr = grow >> 3, hr = grow & 7;
        const int br = pr >> 11, lr = pr & 2047;
        const size_t vb = ((size_t)((br * 8 + hr) * 2048 + lr)) * 32;
        const float rv = Rv[pr];
        sH[(w * 16 + quad * 4 + r) * 32 + l15] = (a0[r] * SQ32 + Va[vb + l15]) * rv;
        sH[(w * 16 + quad * 4 + r) * 32 + 16 + l15] = (a1[r] * SQ32 + Va[vb + 16 + l15]) * rv;
    }
    __syncthreads();

    const int pp = t >> 5, d2 = t & 31;
    const float* hp = sH + pp * 256;
    const float4* wop = (const float4*)(Wo + (size_t)d2 * 256);
    float o = 0.f;
#pragma unroll 8
    for (int j4 = 0; j4 < 64; ++j4) {
        const float4 wv = wop[j4];
        const float4 hv = *(const float4*)(hp + j4 * 4);
        o += wv.x * hv.x + wv.y * hv.y + wv.z * hv.z + wv.w * hv.w;
    }
    out[((size_t)blockIdx.x * 8 + pp) * 32 + d2] = o;
}

extern "C" void kernel_launch(void* const* d_in, const int* in_sizes, int n_in,
                              void* d_out, int out_size, void* d_ws, size_t ws_size,
                              hipStream_t stream) {
    const float* x      = (const float*)d_in[0];
    const void*  mask   = d_in[1];
    const float* Wq     = (const float*)d_in[2];
    const float* Wk     = (const float*)d_in[3];
    const float* Wv     = (const float*)d_in[4];
    const float* Wo     = (const float*)d_in[5];
    const float* cayley = (const float*)d_in[6];
    const float* gs     = (const float*)d_in[7];
    float* out = (float*)d_out;
    float* ws  = (float*)d_ws;
    uint_t* mb = (uint_t*)(ws + MBOFF);

    prep_kernel<<<dim3(1540), dim3(256), 0, stream>>>(
        (const uint_t*)mask, mb, x, Wq, Wk, Wv, gs, cayley, ws);
    attn_kernel<<<dim3(1024), dim3(512), 0, stream>>>(mb, ws);
    gp_kernel<<<dim3(512), dim3(256), 0, stream>>>(ws, Wo, out);
}

// Round 10
// 166.852 us; speedup vs baseline: 1.5501x; 1.5501x over previous
//
#include <hip/hip_runtime.h>
#include <hip/hip_bf16.h>
#include <stdint.h>
#include <stddef.h>

// Problem constants (B=2, L=2048, D=32, H=8)
#define LL 2048

typedef __attribute__((ext_vector_type(8))) short short8;
typedef __attribute__((ext_vector_type(4))) float f32x4;
typedef unsigned short ushort_t;
typedef unsigned int uint_t;

// ws layout (float elements). Total ~17.9 MB.
#define VAOFF   1048576u   // V_agg f32 [bh][l][d]
#define QS16OFF 2097152u   // Q*scale*log2e bf16 [bh][l][d]
#define KS16OFF 2621440u   // K*grade_signs bf16 [bh][l][d]
#define KG16OFF 3145728u   // K raw bf16 [bh][l][d]
#define VT16OFF 3670016u   // V^T bf16 [bh*32+d][l] (key-permuted)
#define RVOFF   4194304u   // row_valid f32, B*L
#define MBOFF   4198400u   // packed mask bits [row][ks][kt], 262144 uint32
#define C2TOFF  4460544u   // cayley^T bf16 [k][ij], 32768 elems

__device__ __forceinline__ ushort_t f2bf(float f) {
    unsigned int u = __float_as_uint(f);
    u += 0x7FFFu + ((u >> 16) & 1u);   // RNE
    return (ushort_t)(u >> 16);
}
__device__ __forceinline__ float bf2f(ushort_t s) {
    return __uint_as_float(((unsigned int)s) << 16);
}
__device__ __forceinline__ uint_t pkbf(float a, float b) {   // RNE pack (one-time)
    __hip_bfloat162 h = __float22bfloat162_rn(float2{a, b});
    return *(uint_t*)&h;
}
// cheap add-half-rounded bf16 pair pack (hot loops)
__device__ __forceinline__ uint_t pk2(float a, float b) {
    const uint_t ua = (__float_as_uint(a) + 0x8000u) >> 16;
    const uint_t ub = (__float_as_uint(b) + 0x8000u) & 0xFFFF0000u;
    return ua | ub;
}

// ---------------------------------------------------------------------------
// Fused prep (r9-proven): [0,1024) mask detect+bit-pack with word order
// index = ks*16 + kt; [1024,1536) QKV 8 pos/block + direct permuted-V^T;
// [1536,1540) cayley^T bf16. Disjoint writes, input-only reads.
// ---------------------------------------------------------------------------
__global__ __launch_bounds__(256) void prep_kernel(
        const uint_t* __restrict__ mraw, uint_t* __restrict__ mb,
        const float* __restrict__ x,
        const float* __restrict__ Wq, const float* __restrict__ Wk,
        const float* __restrict__ Wv, const float* __restrict__ gs,
        const float* __restrict__ cayley, float* __restrict__ ws) {
    __shared__ float smem[8192];
    const int t = threadIdx.x;

    if (blockIdx.x < 1024) {
        int* sI = (int*)smem;
        int* sF = ((int*)smem) + 1;
        if (t == 0) { *sI = 1; *sF = 1; }
        __syncthreads();
        const size_t blk = blockIdx.x;
        const uint4* p8 = (const uint4*)(mraw + blk * 2048 + t * 8);
        const uint4 a = p8[0], c = p8[1];
        const uint_t d8[8] = {a.x, a.y, a.z, a.w, c.x, c.y, c.z, c.w};
        int oi = 1, of = 1;
#pragma unroll
        for (int i = 0; i < 8; ++i) {
            if (d8[i] > 1u) oi = 0;
            if (d8[i] != 0u && d8[i] != 0x3F800000u) of = 0;
        }
        if (!oi) atomicAnd(sI, 0);
        if (!of) atomicAnd(sF, 0);
        __syncthreads();
        const int mtype = *sI ? 1 : (*sF ? 2 : 0);
        uint_t w = 0;
        if (mtype == 0) {
#pragma unroll
            for (int i = 0; i < 8; ++i) {
#pragma unroll
                for (int by = 0; by < 4; ++by)
                    w |= (((d8[i] >> (8 * by)) & 0xFFu) ? 1u : 0u) << (i * 4 + by);
            }
        } else {
            const uint4* pi = (const uint4*)(mraw + blk * 8192 + (size_t)t * 32);
#pragma unroll
            for (int i = 0; i < 8; ++i) {
                const uint4 d = pi[i];
                if (mtype == 1) {
                    w |= (d.x << (i * 4)) | (d.y << (i * 4 + 1)) |
                         (d.z << (i * 4 + 2)) | (d.w << (i * 4 + 3));
                } else {
                    w |= ((d.x ? 1u : 0u) << (i * 4)) | ((d.y ? 1u : 0u) << (i * 4 + 1)) |
                         ((d.z ? 1u : 0u) << (i * 4 + 2)) | ((d.w ? 1u : 0u) << (i * 4 + 3));
                }
            }
        }
        const uint_t W = (uint_t)(blk * 256 + t);
        const uint_t w0 = W & 63u;
        mb[(W & ~63u) | (((w0 & 3u) << 4) | (w0 >> 2))] = w;
    } else if (blockIdx.x < 1536) {
        ushort_t* Qs16 = (ushort_t*)(ws + QS16OFF);
        ushort_t* Ks16 = (ushort_t*)(ws + KS16OFF);
        ushort_t* Kg16 = (ushort_t*)(ws + KG16OFF);
        ushort_t* Vt   = (ushort_t*)(ws + VT16OFF);
        float* sX = smem;
        const int pid0 = (blockIdx.x - 1024) * 8;
        if (t < 64) ((float4*)sX)[t] = ((const float4*)(x + (size_t)pid0 * 32))[t];
        float wq[32], wk[32], wv[32];
        const float4* wqp = (const float4*)(Wq + t * 32);
        const float4* wkp = (const float4*)(Wk + t * 32);
        const float4* wvp = (const float4*)(Wv + t * 32);
#pragma unroll
        for (int d4 = 0; d4 < 8; ++d4) {
            float4 a = wqp[d4]; wq[4*d4]=a.x; wq[4*d4+1]=a.y; wq[4*d4+2]=a.z; wq[4*d4+3]=a.w;
            float4 b = wkp[d4]; wk[4*d4]=b.x; wk[4*d4+1]=b.y; wk[4*d4+2]=b.z; wk[4*d4+3]=b.w;
            float4 c = wvp[d4]; wv[4*d4]=c.x; wv[4*d4+1]=c.y; wv[4*d4+2]=c.z; wv[4*d4+3]=c.w;
        }
        const float sgn = gs[t & 31];
        const float qscale = 0.17677669529663687f * 1.4426950408889634f;
        const int h = t >> 5, dd = t & 31;
        const int b0 = pid0 >> 11, l0 = pid0 & 2047;
        __syncthreads();
        ushort4 vt4[2];
        for (int r = 0; r < 8; ++r) {
            const int pid = pid0 + r;
            const int b = pid >> 11, l = pid & 2047;
            float q = 0.f, k = 0.f, v = 0.f;
#pragma unroll
            for (int d = 0; d < 32; ++d) {
                const float xv = sX[r * 32 + d];
                q += xv * wq[d]; k += xv * wk[d]; v += xv * wv[d];
            }
            const size_t o = ((size_t)((b * 8 + h) * 2048 + l)) * 32 + dd;
            Qs16[o] = f2bf(q * qscale);
            Ks16[o] = f2bf(k * sgn);
            Kg16[o] = f2bf(k);
            ((ushort_t*)&vt4[r >> 2])[r & 3] = f2bf(v);
        }
        ushort_t* vtrow = Vt + ((size_t)((b0 * 8 + h) * 32 + dd)) * 2048;
#pragma unroll
        for (int g4 = 0; g4 < 2; ++g4) {
            const int lg = l0 + g4 * 4;
            const int lloc = lg & 63;
            const int g = lloc >> 5, tt = (lloc >> 4) & 1, q4 = (lloc >> 2) & 3;
            const int pc = (lg & ~63) + g * 32 + q4 * 8 + tt * 4;
            *(ushort4*)(vtrow + pc) = vt4[g4];
        }
    } else {
        float* sC = smem;
        ushort_t* C2t = (ushort_t*)(ws + C2TOFF);
        const int ij0 = (blockIdx.x - 1536) * 256;   // ij in [0,1024)
#pragma unroll
        for (int i = 0; i < 8; ++i)
            ((float4*)sC)[t + i * 256] = ((const float4*)(cayley + (size_t)ij0 * 32))[t + i * 256];
        __syncthreads();
        const int k = t & 31, jc = t >> 5;
        uint_t pk[16];
#pragma unroll
        for (int j2 = 0; j2 < 16; ++j2) {
            pk[j2] = pkbf(sC[(jc * 32 + 2 * j2) * 32 + k], sC[(jc * 32 + 2 * j2 + 1) * 32 + k]);
        }
        uint_t* dst = (uint_t*)(C2t + (size_t)k * 1024 + ij0 + jc * 32);
#pragma unroll
        for (int j2 = 0; j2 < 16; ++j2) dst[j2] = pk[j2];
    }
}

// ---------------------------------------------------------------------------
// Barrier-free MFMA attention, round 10: 4 waves/block (256 thr), wave = ks
// key-quarter; EACH WAVE NOW PROCESSES BOTH Q-ROW HALVES (qfA rows 0..15,
// qfB rows 16..31) against its 32 keys: per iteration 6 loads feed 10 MFMA +
// 16 exp (work per load doubled vs r8). Masks loaded in-loop as single
// dwords (contiguous layout) -- NO hoisting, no full unroll (r9's spill).
// __launch_bounds__(256,4) -> 128 VGPR, no scratch.
// ---------------------------------------------------------------------------
__global__ __launch_bounds__(256, 4) void attn_kernel(
        const uint_t* __restrict__ mb, float* __restrict__ ws) {
    const ushort_t* Qs = (const ushort_t*)(ws + QS16OFF);
    const ushort_t* Ks = (const ushort_t*)(ws + KS16OFF);
    const ushort_t* Vt = (const ushort_t*)(ws + VT16OFF);
    float* Va = ws + VAOFF;
    float* Rv = ws + RVOFF;

    // swizzle: bh = ((bid&7)<<1)|bit9, q0 = ((bid>>3)&63)*32  (bijective)
    const int bid = blockIdx.x;
    const int bh = ((bid & 7) << 1) | ((bid >> 9) & 1);
    const int q0 = ((bid >> 3) & 63) * 32;
    const int b = bh >> 3;
    const int t = threadIdx.x;
    const int ks = t >> 6, lane = t & 63;   // wave = key-quarter
    const int quad = lane >> 4, l15 = lane & 15;

    __shared__ float accb[3][2][64][8];
    __shared__ float psL[4][32];

    // Q B-fragments for both row halves (held all loop)
    const ushort_t* qbase = Qs + ((size_t)(bh * 2048 + q0 + l15)) * 32 + quad * 8;
    const short8 qfA = *(const short8*)(qbase);
    const short8 qfB = *(const short8*)(qbase + 16 * 32);

    const ushort_t* ka_p = Ks + (size_t)bh * 65536 + (ks * 32 + l15) * 32 + quad * 8;
    const ushort_t* v0_p = Vt + (size_t)bh * 65536 + (size_t)l15 * 2048 + ks * 32 + quad * 8;
    const uint_t* m_pA = mb + ((size_t)b * 2048 + q0 + l15) * 64 + ks * 16;
    const uint_t* m_pB = m_pA + 16 * 64;

    f32x4 accA0 = {0.f, 0.f, 0.f, 0.f};
    f32x4 accA1 = {0.f, 0.f, 0.f, 0.f};
    f32x4 accA2 = {0.f, 0.f, 0.f, 0.f};
    f32x4 accB0 = {0.f, 0.f, 0.f, 0.f};
    f32x4 accB1 = {0.f, 0.f, 0.f, 0.f};
    f32x4 accB2 = {0.f, 0.f, 0.f, 0.f};
    const int bp0 = quad * 4, bp1 = 16 + quad * 4;

    union { uint_t u[4]; short8 s; } ONES;
    {
        const uint_t ov = (l15 == 0) ? 0x3F803F80u : 0u;   // bf16 1.0 pair
        ONES.u[0] = ov; ONES.u[1] = ov; ONES.u[2] = ov; ONES.u[3] = ov;
    }

#pragma unroll 2
    for (int kt = 0; kt < 16; ++kt) {
        const short8 ka = *(const short8*)(ka_p + kt * 4096);
        const short8 kb = *(const short8*)(ka_p + kt * 4096 + 512);
        const short8 v0 = *(const short8*)(v0_p + kt * 128);
        const short8 v1 = *(const short8*)(v0_p + 16 * 2048 + kt * 128);
        const uint_t mwA = m_pA[kt];
        const uint_t mwB = m_pB[kt];

        const f32x4 z = {0.f, 0.f, 0.f, 0.f};
        f32x4 s0 = __builtin_amdgcn_mfma_f32_16x16x32_bf16(ka, qfA, z, 0, 0, 0);
        f32x4 s1 = __builtin_amdgcn_mfma_f32_16x16x32_bf16(kb, qfA, z, 0, 0, 0);
        f32x4 s2 = __builtin_amdgcn_mfma_f32_16x16x32_bf16(ka, qfB, z, 0, 0, 0);
        f32x4 s3 = __builtin_amdgcn_mfma_f32_16x16x32_bf16(kb, qfB, z, 0, 0, 0);

        float pA0[4], pA1[4], pB0[4], pB1[4];
#pragma unroll
        for (int r = 0; r < 4; ++r) {
            pA0[r] = ((mwA >> (bp0 + r)) & 1u) ? exp2f(s0[r]) : 0.f;
            pA1[r] = ((mwA >> (bp1 + r)) & 1u) ? exp2f(s1[r]) : 0.f;
            pB0[r] = ((mwB >> (bp0 + r)) & 1u) ? exp2f(s2[r]) : 0.f;
            pB1[r] = ((mwB >> (bp1 + r)) & 1u) ? exp2f(s3[r]) : 0.f;
        }
        union { uint_t u[4]; short8 s; } PA, PB;
        PA.u[0] = pk2(pA0[0], pA0[1]); PA.u[1] = pk2(pA0[2], pA0[3]);
        PA.u[2] = pk2(pA1[0], pA1[1]); PA.u[3] = pk2(pA1[2], pA1[3]);
        PB.u[0] = pk2(pB0[0], pB0[1]); PB.u[1] = pk2(pB0[2], pB0[3]);
        PB.u[2] = pk2(pB1[0], pB1[1]); PB.u[3] = pk2(pB1[2], pB1[3]);

        accA0 = __builtin_amdgcn_mfma_f32_16x16x32_bf16(PA.s, v0, accA0, 0, 0, 0);
        accA1 = __builtin_amdgcn_mfma_f32_16x16x32_bf16(PA.s, v1, accA1, 0, 0, 0);
        accA2 = __builtin_amdgcn_mfma_f32_16x16x32_bf16(PA.s, ONES.s, accA2, 0, 0, 0);
        accB0 = __builtin_amdgcn_mfma_f32_16x16x32_bf16(PB.s, v0, accB0, 0, 0, 0);
        accB1 = __builtin_amdgcn_mfma_f32_16x16x32_bf16(PB.s, v1, accB1, 0, 0, 0);
        accB2 = __builtin_amdgcn_mfma_f32_16x16x32_bf16(PB.s, ONES.s, accB2, 0, 0, 0);
    }

    // partial rowsums (col-0 lanes): accA2[r] = rowsum(q-row quad*4+r)
    if (l15 == 0) {
#pragma unroll
        for (int r = 0; r < 4; ++r) {
            psL[ks][quad * 4 + r] = accA2[r];
            psL[ks][16 + quad * 4 + r] = accB2[r];
        }
    }
    if (ks != 0) {
#pragma unroll
        for (int i = 0; i < 4; ++i) {
            accb[ks - 1][0][lane][i] = accA0[i];
            accb[ks - 1][0][lane][4 + i] = accA1[i];
            accb[ks - 1][1][lane][i] = accB0[i];
            accb[ks - 1][1][lane][4 + i] = accB1[i];
        }
    }
    __syncthreads();
    if (ks == 0) {
#pragma unroll
        for (int p = 0; p < 3; ++p) {
#pragma unroll
            for (int i = 0; i < 4; ++i) {
                accA0[i] += accb[p][0][lane][i];
                accA1[i] += accb[p][0][lane][4 + i];
                accB0[i] += accb[p][1][lane][i];
                accB1[i] += accb[p][1][lane][4 + i];
            }
        }
#pragma unroll
        for (int r = 0; r < 4; ++r) {
            const int rowA = quad * 4 + r;
            const int rowB = 16 + quad * 4 + r;
            const float totA = psL[0][rowA] + psL[1][rowA] + psL[2][rowA] + psL[3][rowA];
            const float totB = psL[0][rowB] + psL[1][rowB] + psL[2][rowB] + psL[3][rowB];
            const float invA = (totA > 0.f) ? 1.0f / totA : 0.f;
            const float invB = (totB > 0.f) ? 1.0f / totB : 0.f;
            const size_t oA = ((size_t)(bh * 2048 + q0 + rowA)) * 32;
            const size_t oB = ((size_t)(bh * 2048 + q0 + rowB)) * 32;
            Va[oA + l15] = accA0[r] * invA;
            Va[oA + 16 + l15] = accA1[r] * invA;
            Va[oB + l15] = accB0[r] * invB;
            Va[oB + 16 + l15] = accB1[r] * invB;
            if ((bh & 7) == 0 && l15 == 0) {
                Rv[(size_t)b * 2048 + q0 + rowA] = (totA > 0.f) ? 1.0f : 0.f;
                Rv[(size_t)b * 2048 + q0 + rowB] = (totB > 0.f) ? 1.0f : 0.f;
            }
        }
    }
}

// ---------------------------------------------------------------------------
// MFMA geometric product + epilogue + Wo (r9-proven: sC stride 1040 ushorts,
// SQ32 * ln2 compensation for the folded log2e).
// ---------------------------------------------------------------------------
__global__ __launch_bounds__(256) void gp_kernel(
        const float* __restrict__ ws, const float* __restrict__ Wo,
        float* __restrict__ out) {
    const float* Va = ws + VAOFF;
    const ushort_t* Qs = (const ushort_t*)(ws + QS16OFF);
    const ushort_t* Kg = (const ushort_t*)(ws + KG16OFF);
    const ushort_t* C2t = (const ushort_t*)(ws + C2TOFF);
    const float* Rv = ws + RVOFF;
    __shared__ ushort_t sC[32 * 1040];
    __shared__ float sH[64 * 32];

    const int t = threadIdx.x;
    const int w = t >> 6, lane = t & 63;
    const int quad = lane >> 4, l15 = lane & 15;

#pragma unroll
    for (int j = 0; j < 16; ++j) {
        const int c = j * 256 + t;
        const int row = c >> 7, col = (c & 127) * 8;
        *(short8*)(&sC[row * 1040 + col]) = *(const short8*)(C2t + row * 1024 + col);
    }

    const int grow0 = blockIdx.x * 64 + w * 16 + l15;
    const int pos = grow0 >> 3, h = grow0 & 7;
    const int b = pos >> 11, l = pos & 2047;
    const size_t gb = ((size_t)((b * 8 + h) * 2048 + l)) * 32;

    float q[32];
#pragma unroll
    for (int j8 = 0; j8 < 4; ++j8) {
        const short8 qv = *(const short8*)(Qs + gb + j8 * 8);
#pragma unroll
        for (int i = 0; i < 8; ++i) q[j8 * 8 + i] = bf2f((ushort_t)qv[i]);
    }
    float u[8];
    {
        const short8 kv = *(const short8*)(Kg + gb + quad * 8);
        const float4 va0 = *(const float4*)(Va + gb + quad * 8);
        const float4 va1 = *(const float4*)(Va + gb + quad * 8 + 4);
        u[0] = va0.x + 0.25f * bf2f((ushort_t)kv[0]);
        u[1] = va0.y + 0.25f * bf2f((ushort_t)kv[1]);
        u[2] = va0.z + 0.25f * bf2f((ushort_t)kv[2]);
        u[3] = va0.w + 0.25f * bf2f((ushort_t)kv[3]);
        u[4] = va1.x + 0.25f * bf2f((ushort_t)kv[4]);
        u[5] = va1.y + 0.25f * bf2f((ushort_t)kv[5]);
        u[6] = va1.z + 0.25f * bf2f((ushort_t)kv[6]);
        u[7] = va1.w + 0.25f * bf2f((ushort_t)kv[7]);
    }
    __syncthreads();

    f32x4 a0 = {0.f, 0.f, 0.f, 0.f};
    f32x4 a1 = {0.f, 0.f, 0.f, 0.f};
    const ushort_t* b0p = sC + (size_t)l15 * 1040 + quad * 8;
    const ushort_t* b1p = sC + (size_t)(16 + l15) * 1040 + quad * 8;

#pragma unroll
    for (int kc = 0; kc < 32; ++kc) {
        const float qk = q[kc];
        union { uint_t u4[4]; short8 s; } F;
        F.u4[0] = pk2(qk * u[0], qk * u[1]);
        F.u4[1] = pk2(qk * u[2], qk * u[3]);
        F.u4[2] = pk2(qk * u[4], qk * u[5]);
        F.u4[3] = pk2(qk * u[6], qk * u[7]);
        const short8 bb0 = *(const short8*)(b0p + kc * 32);
        const short8 bb1 = *(const short8*)(b1p + kc * 32);
        a0 = __builtin_amdgcn_mfma_f32_16x16x32_bf16(F.s, bb0, a0, 0, 0, 0);
        a1 = __builtin_amdgcn_mfma_f32_16x16x32_bf16(F.s, bb1, a1, 0, 0, 0);
    }

    // undo q scale (sqrt(32)) and the folded log2e (x ln2)
    const float SQ32 = 5.656854249492381f * 0.69314718055994531f;
#pragma unroll
    for (int r = 0; r < 4; ++r) {
        const int grow = blockIdx.x * 64 + w * 16 + quad * 4 + r;
        const int pr = grow >> 3, hr = grow & 7;
        const int br = pr >> 11, lr = pr & 2047;
        const size_t vb = ((size_t)((br * 8 + hr) * 2048 + lr)) * 32;
        const float rv = Rv[pr];
        sH[(w * 16 + quad * 4 + r) * 32 + l15] = (a0[r] * SQ32 + Va[vb + l15]) * rv;
        sH[(w * 16 + quad * 4 + r) * 32 + 16 + l15] = (a1[r] * SQ32 + Va[vb + 16 + l15]) * rv;
    }
    __syncthreads();

    const int pp = t >> 5, d2 = t & 31;
    const float* hp = sH + pp * 256;
    const float4* wop = (const float4*)(Wo + (size_t)d2 * 256);
    float o = 0.f;
#pragma unroll 8
    for (int j4 = 0; j4 < 64; ++j4) {
        const float4 wv = wop[j4];
        const float4 hv = *(const float4*)(hp + j4 * 4);
        o += wv.x * hv.x + wv.y * hv.y + wv.z * hv.z + wv.w * hv.w;
    }
    out[((size_t)blockIdx.x * 8 + pp) * 32 + d2] = o;
}

extern "C" void kernel_launch(void* const* d_in, const int* in_sizes, int n_in,
                              void* d_out, int out_size, void* d_ws, size_t ws_size,
                              hipStream_t stream) {
    const float* x      = (const float*)d_in[0];
    const void*  mask   = d_in[1];
    const float* Wq     = (const float*)d_in[2];
    const float* Wk     = (const float*)d_in[3];
    const float* Wv     = (const float*)d_in[4];
    const float* Wo     = (const float*)d_in[5];
    const float* cayley = (const float*)d_in[6];
    const float* gs     = (const float*)d_in[7];
    float* out = (float*)d_out;
    float* ws  = (float*)d_ws;
    uint_t* mb = (uint_t*)(ws + MBOFF);

    prep_kernel<<<dim3(1540), dim3(256), 0, stream>>>(
        (const uint_t*)mask, mb, x, Wq, Wk, Wv, gs, cayley, ws);
    attn_kernel<<<dim3(1024), dim3(256), 0, stream>>>(mb, ws);
    gp_kernel<<<dim3(512), dim3(256), 0, stream>>>(ws, Wo, out);
}